// Round 7
// baseline (599.215 us; speedup 1.0000x reference)
//
#include <hip/hip_runtime.h>

#define BB 4
#define SS 2048
#define DD 256
#define HH 8

typedef unsigned short u16;
typedef __attribute__((ext_vector_type(8))) short bf16x8;
typedef __attribute__((ext_vector_type(4))) float f32x4;

__device__ __forceinline__ f32x4 MFMA(bf16x8 a, bf16x8 b, f32x4 c) {
    return __builtin_amdgcn_mfma_f32_16x16x32_bf16(a, b, c, 0, 0, 0);
}

__device__ __forceinline__ u16 f2bf_rtn(float x) {
    unsigned u = __float_as_uint(x);
    u += 0x7FFFu + ((u >> 16) & 1u);
    return (u16)(u >> 16);
}
__device__ __forceinline__ float bf2f(u16 h) {
    return __uint_as_float(((unsigned)h) << 16);
}
__device__ __forceinline__ void split2(float x, u16 &hi, u16 &lo) {
    hi = f2bf_rtn(x);
    lo = f2bf_rtn(x - bf2f(hi));
}

// ---------------- weight prep: transpose + hi/lo split ----------------
__global__ void prep_w(const float* __restrict__ W, u16* __restrict__ Whi,
                       u16* __restrict__ Wlo) {
    int n = blockIdx.x;            // 0..2047
    int h = n >> 8, e = n & 255;
    int d = threadIdx.x;           // 0..255
    float x = W[((size_t)h * 256 + d) * 256 + e];
    u16 hi, lo; split2(x, hi, lo);
    Whi[(size_t)n * 256 + d] = hi;
    Wlo[(size_t)n * 256 + d] = lo;
}

__global__ void prep_wo(const float* __restrict__ W, u16* __restrict__ Whi,
                        u16* __restrict__ Wlo) {
    int n = blockIdx.x;            // 0..255
    for (int k = threadIdx.x; k < 2048; k += 256) {
        float x = W[(size_t)k * 256 + n];
        u16 hi, lo; split2(x, hi, lo);
        Whi[(size_t)n * 2048 + k] = hi;
        Wlo[(size_t)n * 2048 + k] = lo;
    }
}

// ---------------- split-bf16 GEMM: C = A * B^T(stored [N][K]) + bias ----------------
template<int MODE, bool AFP32, int TERMS, int BN>
__global__ __launch_bounds__(512, 2) void gemm_split(
    const float* __restrict__ Af,
    const u16* __restrict__ Ahi, const u16* __restrict__ Alo,
    const u16* __restrict__ Bhi, const u16* __restrict__ Blo,
    const float* __restrict__ bias,
    u16* __restrict__ Ohi,
    float* __restrict__ Of,
    int M, int N, int K, float scale)
{
    constexpr int WN = (BN == 128) ? 4 : 2;
    constexpr int WM = 8 / WN;
    constexpr int MSUB = (128 / WM) / 16;
    constexpr int NSUB = (BN / WN) / 16;

    __shared__ u16 lA_hi[128][40], lA_lo[128][40];
    __shared__ u16 lB_hi[128][40], lB_lo[128][40];

    const int tid = threadIdx.x;
    const int lane = tid & 63, wave = tid >> 6;
    const int wm = wave / WN, wn = wave % WN;
    const int m0 = blockIdx.y * 128, n0 = blockIdx.x * BN;

    f32x4 acc[MSUB][NSUB];
#pragma unroll
    for (int i = 0; i < MSUB; ++i)
#pragma unroll
        for (int j = 0; j < NSUB; ++j) acc[i][j] = {0.f, 0.f, 0.f, 0.f};

    const int srow = tid >> 2;
    const int schunk = (tid & 3) * 8;

    for (int k0 = 0; k0 < K; k0 += 32) {
        __syncthreads();
        if (AFP32) {
            const float* g = Af + (size_t)(m0 + srow) * K + k0 + schunk;
            f32x4 a0 = *(const f32x4*)g;
            f32x4 a1 = *(const f32x4*)(g + 4);
            bf16x8 hv;
#pragma unroll
            for (int j = 0; j < 4; ++j) hv[j] = (short)f2bf_rtn(a0[j]);
#pragma unroll
            for (int j = 0; j < 4; ++j) hv[4 + j] = (short)f2bf_rtn(a1[j]);
            *(bf16x8*)&lA_hi[srow][schunk] = hv;
        } else {
            size_t ga = (size_t)(m0 + srow) * K + k0 + schunk;
            *(bf16x8*)&lA_hi[srow][schunk] = *(const bf16x8*)(Ahi + ga);
            if (TERMS == 3)
                *(bf16x8*)&lA_lo[srow][schunk] = *(const bf16x8*)(Alo + ga);
        }
        if (BN == 128 || tid < BN * 4) {
            size_t gb = (size_t)(n0 + srow) * K + k0 + schunk;
            *(bf16x8*)&lB_hi[srow][schunk] = *(const bf16x8*)(Bhi + gb);
            if (TERMS >= 2)
                *(bf16x8*)&lB_lo[srow][schunk] = *(const bf16x8*)(Blo + gb);
        }
        __syncthreads();

        const int kf = (lane >> 4) * 8;
        const int rA = wm * (128 / WM), rB = wn * (BN / WN);
        bf16x8 bh[NSUB], bl[NSUB];
#pragma unroll
        for (int ns = 0; ns < NSUB; ++ns) {
            bh[ns] = *(bf16x8*)&lB_hi[rB + ns * 16 + (lane & 15)][kf];
            if (TERMS >= 2)
                bl[ns] = *(bf16x8*)&lB_lo[rB + ns * 16 + (lane & 15)][kf];
        }
#pragma unroll
        for (int ms = 0; ms < MSUB; ++ms) {
            bf16x8 ah = *(bf16x8*)&lA_hi[rA + ms * 16 + (lane & 15)][kf];
            bf16x8 al;
            if (TERMS == 3) al = *(bf16x8*)&lA_lo[rA + ms * 16 + (lane & 15)][kf];
#pragma unroll
            for (int ns = 0; ns < NSUB; ++ns) {
                acc[ms][ns] = MFMA(ah, bh[ns], acc[ms][ns]);
                if (TERMS == 3) acc[ms][ns] = MFMA(al, bh[ns], acc[ms][ns]);
                if (TERMS >= 2) acc[ms][ns] = MFMA(ah, bl[ns], acc[ms][ns]);
            }
        }
    }

#pragma unroll
    for (int ms = 0; ms < MSUB; ++ms)
#pragma unroll
        for (int ns = 0; ns < NSUB; ++ns)
#pragma unroll
            for (int r = 0; r < 4; ++r) {
                int row = m0 + wm * (128 / WM) + ms * 16 + (lane >> 4) * 4 + r;
                int col = n0 + wn * (BN / WN) + ns * 16 + (lane & 15);
                float v = (acc[ms][ns][r] + bias[col]) * scale;
                if (MODE == 2) {
                    Of[(size_t)row * N + col] = v;
                } else {
                    int b = row >> 11, s = row & 2047, hh = col >> 8, e = col & 255;
                    size_t idx;
                    if (MODE == 0)
                        idx = ((size_t)(b * HH + hh) * SS + s) * DD + e;
                    else
                        idx = ((size_t)(b * HH + hh) * DD + e) * SS + s;
                    Ohi[idx] = f2bf_rtn(v);
                }
            }
}

// ---------------- flash attention: 4-wave blocks, 2 blocks/CU, fixed-m softmax ----------------
// Swapped QK^T; fixed softmax reference m=8 (log2 domain): no online max, no rescale,
// l-reduction deferred to epilogue. 1-D grid of 512 with bijective XCD swizzle so each
// XCD holds 4 bh x 16 q-tiles (K/V L2 locality). Two independent blocks per CU ->
// barrier-stall windows of one block overlap with compute of the other.
// K LDS [32][264], row r's 16B-slot X stored at X^rho(r), rho(r)=((r>>3)&3)<<1.
// V LDS [256][40]. Double-buffered, one __syncthreads per tile.
__global__ __launch_bounds__(256, 2) void attn_kernel(
    const u16* __restrict__ Qhi,
    const u16* __restrict__ Khi,
    const u16* __restrict__ Vhi,
    u16* __restrict__ Rhi, u16* __restrict__ Rlo)
{
    __shared__ u16 lK[2][32][264];
    __shared__ u16 lV[2][256][40];

    const int tid = threadIdx.x, lane = tid & 63, wave = tid >> 6;
    const int m = lane & 15, g = lane >> 4;
    // XCD-aware swizzle: wg = (bid%8)*64 + bid/8; bh-major within each XCD chunk
    const int wg = ((blockIdx.x & 7) << 6) + (blockIdx.x >> 3);
    const int bh = wg >> 4;                        // 0..31 (b*8+h)
    const int qt = wg & 15;                        // 0..15
    const size_t base = (size_t)bh * SS * DD;
    const int q0 = qt * 128 + wave * 32;

    // Q fragments, 2 q-groups of 16 (B-operand: col=q=m, d-chunk g*8 within ks*32)
    bf16x8 qh[2][8];
#pragma unroll
    for (int qg = 0; qg < 2; ++qg)
#pragma unroll
        for (int ks = 0; ks < 8; ++ks)
            qh[qg][ks] = *(const bf16x8*)(Qhi + base +
                (size_t)(q0 + qg * 16 + m) * DD + ks * 32 + g * 8);

    // K-frag read coords: rows r0, r0+4; col slot X = ((ks<<2)|g) ^ rho, rho=(m>>2)<<1
    const int r0 = ((m >> 2) << 3) + (m & 3);
    const int rho = (m >> 2) << 1;

    // staging coords: 4 K-chunks + 4 V-chunks per thread (256 threads)
    int kd[4], kg[4], vd[4];
    size_t vg[4];
#pragma unroll
    for (int i = 0; i < 4; ++i) {
        const int ck = tid + i * 256;              // K chunk id 0..1023
        const int kr = ck >> 5, kc = ck & 31;
        kd[i] = kr * 264 + ((kc ^ (((kr >> 3) & 3) << 1)) << 3);
        kg[i] = kr * 256 + (kc << 3);
        const int vr = ck >> 2, vc = ck & 3;       // V chunk id
        vd[i] = vr * 40 + (vc << 3);
        vg[i] = (size_t)vr * SS + (vc << 3);
    }

    f32x4 lsum[2] = {{0.f,0.f,0.f,0.f}, {0.f,0.f,0.f,0.f}};
    f32x4 acc[2][16];
#pragma unroll
    for (int qg = 0; qg < 2; ++qg)
#pragma unroll
        for (int e = 0; e < 16; ++e) acc[qg][e] = {0.f, 0.f, 0.f, 0.f};

    bf16x8 rk[4], rv[4];
#define ISSUE_LOADS(kvn)                                                        \
    {   const u16* Kg = Khi + base + (size_t)(kvn) * DD;                        \
        const u16* Vg = Vhi + base + (kvn);                                     \
        _Pragma("unroll")                                                       \
        for (int i = 0; i < 4; ++i) {                                           \
            rk[i] = *(const bf16x8*)(Kg + kg[i]);                               \
            rv[i] = *(const bf16x8*)(Vg + vg[i]);                               \
        }                                                                       \
    }
#define WRITE_BUF(p)                                                            \
    {   u16* Kb = &lK[p][0][0]; u16* Vb = &lV[p][0][0];                         \
        _Pragma("unroll")                                                       \
        for (int i = 0; i < 4; ++i) {                                           \
            *(bf16x8*)(Kb + kd[i]) = rk[i];                                     \
            *(bf16x8*)(Vb + vd[i]) = rv[i];                                     \
        }                                                                       \
    }

    ISSUE_LOADS(0);
    WRITE_BUF(0);
    __syncthreads();

    for (int t = 0; t < 64; ++t) {
        if (t < 63) ISSUE_LOADS((t + 1) * 32);

        const u16* Kb = &lK[t & 1][0][0];
        const u16* Vb = &lV[t & 1][0][0];

        // QK^T: s[qg][t2] -> keys 8g+r+4*t2 for q = q0+qg*16+m
        f32x4 s[2][2];
        s[0][0] = {0.f,0.f,0.f,0.f}; s[0][1] = {0.f,0.f,0.f,0.f};
        s[1][0] = {0.f,0.f,0.f,0.f}; s[1][1] = {0.f,0.f,0.f,0.f};
        __builtin_amdgcn_s_setprio(1);
#pragma unroll
        for (int ks = 0; ks < 8; ++ks) {
            const int c0 = ((((ks << 2) | g) ^ rho)) << 3;
            bf16x8 k0 = *(const bf16x8*)(Kb + r0 * 264 + c0);
            bf16x8 k1 = *(const bf16x8*)(Kb + (r0 + 4) * 264 + c0);
            s[0][0] = MFMA(k0, qh[0][ks], s[0][0]);
            s[0][1] = MFMA(k1, qh[0][ks], s[0][1]);
            s[1][0] = MFMA(k0, qh[1][ks], s[1][0]);
            s[1][1] = MFMA(k1, qh[1][ks], s[1][1]);
        }
        __builtin_amdgcn_s_setprio(0);

        // fixed-m softmax: P = exp2(s - 8); l deferred (pure lane-local sums)
        bf16x8 pb[2];
#pragma unroll
        for (int qg = 0; qg < 2; ++qg) {
#pragma unroll
            for (int t2 = 0; t2 < 2; ++t2)
#pragma unroll
                for (int r = 0; r < 4; ++r)
                    s[qg][t2][r] = __builtin_amdgcn_exp2f(s[qg][t2][r] - 8.0f);
            lsum[qg] += s[qg][0] + s[qg][1];
#pragma unroll
            for (int j = 0; j < 4; ++j) pb[qg][j] = (short)f2bf_rtn(s[qg][0][j]);
#pragma unroll
            for (int j = 0; j < 4; ++j) pb[qg][4 + j] = (short)f2bf_rtn(s[qg][1][j]);
        }

        // PV: acc[qg][e16] += V^T-frag * P-frag (V-frag shared across q-groups)
        __builtin_amdgcn_s_setprio(1);
#pragma unroll
        for (int e16 = 0; e16 < 16; ++e16) {
            bf16x8 vf = *(const bf16x8*)(Vb + e16 * 640 + m * 40 + (g << 3));
            acc[0][e16] = MFMA(vf, pb[0], acc[0][e16]);
            acc[1][e16] = MFMA(vf, pb[1], acc[1][e16]);
        }
        __builtin_amdgcn_s_setprio(0);

        if (t < 63) WRITE_BUF((t + 1) & 1);
        __syncthreads();
    }
#undef ISSUE_LOADS
#undef WRITE_BUF

    // epilogue: reduce l (components + lanes m+16g), then scale and store
    const int b = bh >> 3, h = bh & 7;
#pragma unroll
    for (int qg = 0; qg < 2; ++qg) {
        float l = (lsum[qg][0] + lsum[qg][1]) + (lsum[qg][2] + lsum[qg][3]);
        l += __shfl_xor(l, 16);
        l += __shfl_xor(l, 32);
        float inv = 1.0f / l;
        const size_t rowbase = ((size_t)(b * SS + q0 + qg * 16 + m)) * (DD * HH) + h;
#pragma unroll
        for (int e16 = 0; e16 < 16; ++e16)
#pragma unroll
            for (int r = 0; r < 4; ++r) {
                int e = e16 * 16 + g * 4 + r;
                float v = acc[qg][e16][r] * inv;
                u16 hh2, ll2; split2(v, hh2, ll2);
                Rhi[rowbase + (size_t)e * HH] = hh2;
                Rlo[rowbase + (size_t)e * HH] = ll2;
            }
    }
}

// ---------------- launcher ----------------
extern "C" void kernel_launch(void* const* d_in, const int* in_sizes, int n_in,
                              void* d_out, int out_size, void* d_ws, size_t ws_size,
                              hipStream_t stream)
{
    (void)in_sizes; (void)n_in; (void)out_size; (void)ws_size;
    const float* k_in = (const float*)d_in[0];
    const float* v_in = (const float*)d_in[1];
    const float* q_in = (const float*)d_in[2];
    const float* Wk   = (const float*)d_in[3];
    const float* bk   = (const float*)d_in[4];
    const float* Wv   = (const float*)d_in[5];
    const float* bv   = (const float*)d_in[6];
    const float* Wq   = (const float*)d_in[7];
    const float* bq   = (const float*)d_in[8];
    const float* Wo   = (const float*)d_in[9];
    const float* bo   = (const float*)d_in[10];
    float* out = (float*)d_out;

    char* p = (char*)d_ws;
    const size_t MB = 1024 * 1024;
    u16* WqH = (u16*)(p + 0 * MB);
    u16* WqL = (u16*)(p + 1 * MB);
    u16* WkH = (u16*)(p + 2 * MB);
    u16* WkL = (u16*)(p + 3 * MB);
    u16* WvH = (u16*)(p + 4 * MB);
    u16* WvL = (u16*)(p + 5 * MB);
    u16* WoH = (u16*)(p + 6 * MB);
    u16* WoL = (u16*)(p + 7 * MB);
    const size_t PB = 32 * MB;
    u16* QH  = (u16*)(p + 8 * MB);
    u16* KH  = (u16*)(p + 8 * MB + 1 * PB);
    u16* VTH = (u16*)(p + 8 * MB + 2 * PB);
    u16* RH  = (u16*)(p + 8 * MB + 3 * PB);
    u16* RL  = (u16*)(p + 8 * MB + 4 * PB);

    prep_w<<<dim3(2048), dim3(256), 0, stream>>>(Wq, WqH, WqL);
    prep_w<<<dim3(2048), dim3(256), 0, stream>>>(Wk, WkH, WkL);
    prep_w<<<dim3(2048), dim3(256), 0, stream>>>(Wv, WvH, WvL);
    prep_wo<<<dim3(256), dim3(256), 0, stream>>>(Wo, WoH, WoL);

    // projections: M=8192, N=2048, K=256.
    // Q scaled by log2(e)/sqrt(D) -> logits directly in log2 domain.
    const float qscale = 1.4426950408889634f / 16.0f;
    gemm_split<0, true, 1, 128><<<dim3(16, 64), dim3(512), 0, stream>>>(
        q_in, nullptr, nullptr, WqH, WqL, bq, QH, nullptr, 8192, 2048, 256, qscale);
    gemm_split<0, true, 1, 128><<<dim3(16, 64), dim3(512), 0, stream>>>(
        k_in, nullptr, nullptr, WkH, WkL, bk, KH, nullptr, 8192, 2048, 256, 1.0f);
    gemm_split<1, true, 2, 128><<<dim3(16, 64), dim3(512), 0, stream>>>(
        v_in, nullptr, nullptr, WvH, WvL, bv, VTH, nullptr, 8192, 2048, 256, 1.0f);

    // flash attention: 512 blocks (16 q-tiles x 32 bh), XCD-swizzled, 2 blocks/CU
    attn_kernel<<<dim3(512), dim3(256), 0, stream>>>(
        QH, KH, VTH, RH, RL);

    // output projection: M=8192, N=256, K=2048; 128x64 tiles -> 256 blocks
    gemm_split<2, false, 3, 64><<<dim3(4, 64), dim3(512), 0, stream>>>(
        nullptr, RH, RL, WoH, WoL, bo, nullptr, out, 8192, 256, 2048, 1.0f);
}

// Round 8
// 378.657 us; speedup vs baseline: 1.5825x; 1.5825x over previous
//
#include <hip/hip_runtime.h>

#define BB 4
#define SS 2048
#define DD 256
#define HH 8

typedef unsigned short u16;
typedef __attribute__((ext_vector_type(8))) short bf16x8;
typedef __attribute__((ext_vector_type(4))) float f32x4;
typedef __attribute__((ext_vector_type(16))) float f32x16;
typedef __attribute__((ext_vector_type(4))) short s16x4;

__device__ __forceinline__ f32x4 MFMA(bf16x8 a, bf16x8 b, f32x4 c) {
    return __builtin_amdgcn_mfma_f32_16x16x32_bf16(a, b, c, 0, 0, 0);
}
__device__ __forceinline__ f32x16 MFMA32(bf16x8 a, bf16x8 b, f32x16 c) {
    return __builtin_amdgcn_mfma_f32_32x32x16_bf16(a, b, c, 0, 0, 0);
}

__device__ __forceinline__ u16 f2bf_rtn(float x) {
    unsigned u = __float_as_uint(x);
    u += 0x7FFFu + ((u >> 16) & 1u);
    return (u16)(u >> 16);
}
__device__ __forceinline__ float bf2f(u16 h) {
    return __uint_as_float(((unsigned)h) << 16);
}
__device__ __forceinline__ void split2(float x, u16 &hi, u16 &lo) {
    hi = f2bf_rtn(x);
    lo = f2bf_rtn(x - bf2f(hi));
}

// async global->LDS, 16B per lane; LDS dest = wave-uniform base + lane*16
__device__ __forceinline__ void gl_lds16(const u16* g, u16* l) {
    __builtin_amdgcn_global_load_lds(
        (const __attribute__((address_space(1))) unsigned int*)(g),
        (__attribute__((address_space(3))) unsigned int*)(l), 16, 0, 0);
}

// ---------------- weight prep ----------------
__global__ void prep_w(const float* __restrict__ W, u16* __restrict__ Whi,
                       u16* __restrict__ Wlo) {
    int n = blockIdx.x;            // 0..2047
    int h = n >> 8, e = n & 255;
    int d = threadIdx.x;           // 0..255
    float x = W[((size_t)h * 256 + d) * 256 + e];
    u16 hi, lo; split2(x, hi, lo);
    Whi[(size_t)n * 256 + d] = hi;
    Wlo[(size_t)n * 256 + d] = lo;
}

// Wo [2048][256] (row = d*8+h) -> Wot[e][h*256+d]
__global__ void prep_wo(const float* __restrict__ W, u16* __restrict__ Whi,
                        u16* __restrict__ Wlo) {
    int n = blockIdx.x;            // e: 0..255
    for (int k = threadIdx.x; k < 2048; k += 256) {
        int d = k & 255, h = k >> 8;
        float x = W[((size_t)(d * 8 + h)) * 256 + n];
        u16 hi, lo; split2(x, hi, lo);
        Whi[(size_t)n * 2048 + k] = hi;
        Wlo[(size_t)n * 2048 + k] = lo;
    }
}

// ---------------- split-bf16 GEMM: C = A * B^T(stored [N][K]) + bias ----------------
// MODE 0: bf16-hi out -> [b][h][s][d]; MODE 1: -> V^T [b][h][d][s]; MODE 2: fp32 out
// AMODE 0: A fp32 [row][k]; AMODE 2: A = R planes [b][h][s][d], k = h*256+d
template<int MODE, int AMODE, int TERMS, int BN>
__global__ __launch_bounds__(512, 2) void gemm_split(
    const float* __restrict__ Af,
    const u16* __restrict__ Ahi, const u16* __restrict__ Alo,
    const u16* __restrict__ Bhi, const u16* __restrict__ Blo,
    const float* __restrict__ bias,
    u16* __restrict__ Ohi,
    float* __restrict__ Of,
    int M, int N, int K, float scale)
{
    constexpr int WN = (BN == 128) ? 4 : 2;
    constexpr int WM = 8 / WN;
    constexpr int MSUB = (128 / WM) / 16;
    constexpr int NSUB = (BN / WN) / 16;

    __shared__ u16 lA_hi[128][40], lA_lo[128][40];
    __shared__ u16 lB_hi[128][40], lB_lo[128][40];

    const int tid = threadIdx.x;
    const int lane = tid & 63, wave = tid >> 6;
    const int wm = wave / WN, wn = wave % WN;
    const int m0 = blockIdx.y * 128, n0 = blockIdx.x * BN;

    f32x4 acc[MSUB][NSUB];
#pragma unroll
    for (int i = 0; i < MSUB; ++i)
#pragma unroll
        for (int j = 0; j < NSUB; ++j) acc[i][j] = {0.f, 0.f, 0.f, 0.f};

    const int srow = tid >> 2;
    const int schunk = (tid & 3) * 8;

    for (int k0 = 0; k0 < K; k0 += 32) {
        __syncthreads();
        if (AMODE == 0) {
            const float* g = Af + (size_t)(m0 + srow) * K + k0 + schunk;
            f32x4 a0 = *(const f32x4*)g;
            f32x4 a1 = *(const f32x4*)(g + 4);
            bf16x8 hv;
#pragma unroll
            for (int j = 0; j < 4; ++j) hv[j] = (short)f2bf_rtn(a0[j]);
#pragma unroll
            for (int j = 0; j < 4; ++j) hv[4 + j] = (short)f2bf_rtn(a1[j]);
            *(bf16x8*)&lA_hi[srow][schunk] = hv;
        } else {
            size_t ga;
            if (AMODE == 2)
                ga = ((size_t)((m0 >> 11) * 8 + (k0 >> 8)) * SS + (m0 & 2047) + srow) * DD
                     + (k0 & 255) + schunk;
            else
                ga = (size_t)(m0 + srow) * K + k0 + schunk;
            *(bf16x8*)&lA_hi[srow][schunk] = *(const bf16x8*)(Ahi + ga);
            if (TERMS == 3)
                *(bf16x8*)&lA_lo[srow][schunk] = *(const bf16x8*)(Alo + ga);
        }
        if (BN == 128 || tid < BN * 4) {
            size_t gb = (size_t)(n0 + srow) * K + k0 + schunk;
            *(bf16x8*)&lB_hi[srow][schunk] = *(const bf16x8*)(Bhi + gb);
            if (TERMS >= 2)
                *(bf16x8*)&lB_lo[srow][schunk] = *(const bf16x8*)(Blo + gb);
        }
        __syncthreads();

        const int kf = (lane >> 4) * 8;
        const int rA = wm * (128 / WM), rB = wn * (BN / WN);
        bf16x8 bh[NSUB], bl[NSUB];
#pragma unroll
        for (int ns = 0; ns < NSUB; ++ns) {
            bh[ns] = *(bf16x8*)&lB_hi[rB + ns * 16 + (lane & 15)][kf];
            if (TERMS >= 2)
                bl[ns] = *(bf16x8*)&lB_lo[rB + ns * 16 + (lane & 15)][kf];
        }
#pragma unroll
        for (int ms = 0; ms < MSUB; ++ms) {
            bf16x8 ah = *(bf16x8*)&lA_hi[rA + ms * 16 + (lane & 15)][kf];
            bf16x8 al;
            if (TERMS == 3) al = *(bf16x8*)&lA_lo[rA + ms * 16 + (lane & 15)][kf];
#pragma unroll
            for (int ns = 0; ns < NSUB; ++ns) {
                acc[ms][ns] = MFMA(ah, bh[ns], acc[ms][ns]);
                if (TERMS == 3) acc[ms][ns] = MFMA(al, bh[ns], acc[ms][ns]);
                if (TERMS >= 2) acc[ms][ns] = MFMA(ah, bl[ns], acc[ms][ns]);
            }
        }
    }

#pragma unroll
    for (int ms = 0; ms < MSUB; ++ms)
#pragma unroll
        for (int ns = 0; ns < NSUB; ++ns)
#pragma unroll
            for (int r = 0; r < 4; ++r) {
                int row = m0 + wm * (128 / WM) + ms * 16 + (lane >> 4) * 4 + r;
                int col = n0 + wn * (BN / WN) + ns * 16 + (lane & 15);
                float v = (acc[ms][ns][r] + bias[col]) * scale;
                if (MODE == 2) {
                    Of[(size_t)row * N + col] = v;
                } else {
                    int b = row >> 11, s = row & 2047, hh = col >> 8, e = col & 255;
                    size_t idx;
                    if (MODE == 0)
                        idx = ((size_t)(b * HH + hh) * SS + s) * DD + e;
                    else
                        idx = ((size_t)(b * HH + hh) * DD + e) * SS + s;
                    Ohi[idx] = f2bf_rtn(v);
                }
            }
}

// ---------------- flash attention: 32x32x16 MFMA, global_load_lds, fixed-m softmax ----
// 4 waves x 32 q = 128 q/block; KVBLK=32; 2 blocks/CU (64 KB LDS each).
// Swapped QK^T with key permutation kappa = swap bits 2<->3 (involution), which makes
// the exp'd S^T registers sequential PV B-fragments: pb_kc[j] = s[8*kc + j].
// K LDS [32][256]: row r holds key kappa(r), 16B-slot X stores d-slot X^r.
// V LDS [256][32]: row e, slot Xs stores k-slot Xs^((e>>3)&3). Both: reads and the
// lane-linear global_load_lds writes hit exactly 2 lanes per 16B slot (conflict-free).
// Fixed softmax ref m=8 (log2-domain logits, |s|<<8): no max, no rescale; l deferred.
__global__ __launch_bounds__(256, 2) void attn_kernel(
    const u16* __restrict__ Qhi,
    const u16* __restrict__ Khi,
    const u16* __restrict__ Vhi,
    u16* __restrict__ Rhi, u16* __restrict__ Rlo)
{
    __shared__ u16 lK[2][32][256];
    __shared__ u16 lV[2][256][32];

    const int tid = threadIdx.x, lane = tid & 63, wave = tid >> 6;
    const int qc = lane & 31, g2 = lane >> 5;
    const int bh = blockIdx.y;                     // 0..31
    const size_t base = (size_t)bh * SS * DD;
    const int q0w = blockIdx.x * 128 + wave * 32;

    // Q as B-operand: lane holds Q[d = ks*16 + g2*8 + j][q = qc]
    bf16x8 qB[16];
#pragma unroll
    for (int ks = 0; ks < 16; ++ks)
        qB[ks] = *(const bf16x8*)(Qhi + base + (size_t)(q0w + qc) * DD + ks * 16 + g2 * 8);

    // per-lane global source offsets for the 8 gl_lds16 issues (K:4, V:4)
    int koff[4], voff[4];
#pragma unroll
    for (int q = 0; q < 4; ++q) {
        const int s = wave * 256 + q * 64 + lane;  // linear 16B-slot in 16KB image
        const int kr = s >> 5, kX = s & 31;
        const int kap = (kr & 0x13) | ((kr & 4) << 1) | ((kr & 8) >> 1);
        koff[q] = kap * DD + ((kX ^ kr) << 3);
        const int ve = s >> 2, vXs = s & 3;
        voff[q] = ve * SS + (((vXs ^ ((ve >> 3) & 3))) << 3);
    }

    float l_part = 0.f;
    f32x16 acc[8];
#pragma unroll
    for (int ec = 0; ec < 8; ++ec) acc[ec] = {};

#define ISSUE(tt, p)                                                            \
    {   const u16* Kg = Khi + base + (size_t)(tt) * 32 * DD;                    \
        const u16* Vg = Vhi + base + (size_t)(tt) * 32;                         \
        u16* Kb = &lK[p][0][0]; u16* Vb = &lV[p][0][0];                         \
        _Pragma("unroll")                                                       \
        for (int q = 0; q < 4; ++q) {                                           \
            gl_lds16(Kg + koff[q], Kb + (wave * 4 + q) * 512);                  \
            gl_lds16(Vg + voff[q], Vb + (wave * 4 + q) * 512);                  \
        }                                                                       \
    }

    ISSUE(0, 0);
    __syncthreads();

    for (int t = 0; t < 64; ++t) {
        if (t < 63) ISSUE(t + 1, (t + 1) & 1);

        const u16* Kb = &lK[t & 1][0][0];
        const u16* Vb = &lV[t & 1][0][0];

        // QK^T: two independent 8-chains over d (d-split), merged after
        f32x16 sa = {}, sb = {};
        __builtin_amdgcn_s_setprio(1);
#pragma unroll
        for (int ks = 0; ks < 8; ++ks) {
            bf16x8 ka = *(const bf16x8*)(Kb + qc * DD + (((2 * ks + g2) ^ qc) << 3));
            bf16x8 kb2 = *(const bf16x8*)(Kb + qc * DD + (((2 * (ks + 8) + g2) ^ qc) << 3));
            sa = MFMA32(ka, qB[ks], sa);
            sb = MFMA32(kb2, qB[ks + 8], sb);
        }
        __builtin_amdgcn_s_setprio(0);

        // fixed-m softmax in log2 domain; l deferred (lane-local scalar)
        f32x16 s = sa + sb;
#pragma unroll
        for (int n = 0; n < 16; ++n) s[n] = __builtin_amdgcn_exp2f(s[n] - 8.0f);
        float tl = 0.f;
#pragma unroll
        for (int n = 0; n < 16; ++n) tl += s[n];
        l_part += tl;

        bf16x8 p0, p1;
#pragma unroll
        for (int j = 0; j < 8; ++j) p0[j] = (short)f2bf_rtn(s[j]);
#pragma unroll
        for (int j = 0; j < 8; ++j) p1[j] = (short)f2bf_rtn(s[8 + j]);

        // PV: acc[ec] over e = ec*32 + row
        __builtin_amdgcn_s_setprio(1);
#pragma unroll
        for (int ec = 0; ec < 8; ++ec) {
            const int e = ec * 32 + qc;
            bf16x8 v0 = *(const bf16x8*)(Vb + e * 32 + (((g2 ^ ((e >> 3) & 3))) << 3));
            bf16x8 v1 = *(const bf16x8*)(Vb + e * 32 + ((((2 + g2) ^ ((e >> 3) & 3))) << 3));
            acc[ec] = MFMA32(v0, p0, acc[ec]);
            acc[ec] = MFMA32(v1, p1, acc[ec]);
        }
        __builtin_amdgcn_s_setprio(0);

        __syncthreads();
    }
#undef ISSUE

    // epilogue: l = own half + partner half (lane^32 shares qc); store R [bh][s][d]
    float l = l_part + __shfl_xor(l_part, 32);
    float inv = 1.0f / l;
    const size_t rowbase = ((size_t)bh * SS + q0w + qc) * DD;
#pragma unroll
    for (int ec = 0; ec < 8; ++ec)
#pragma unroll
        for (int rr = 0; rr < 4; ++rr) {
            const int e0 = ec * 32 + 8 * rr + 4 * g2;
            s16x4 hv, lv;
#pragma unroll
            for (int j = 0; j < 4; ++j) {
                u16 h2, l2; split2(acc[ec][4 * rr + j] * inv, h2, l2);
                hv[j] = (short)h2; lv[j] = (short)l2;
            }
            *(s16x4*)(Rhi + rowbase + e0) = hv;
            *(s16x4*)(Rlo + rowbase + e0) = lv;
        }
}

// ---------------- launcher ----------------
extern "C" void kernel_launch(void* const* d_in, const int* in_sizes, int n_in,
                              void* d_out, int out_size, void* d_ws, size_t ws_size,
                              hipStream_t stream)
{
    (void)in_sizes; (void)n_in; (void)out_size; (void)ws_size;
    const float* k_in = (const float*)d_in[0];
    const float* v_in = (const float*)d_in[1];
    const float* q_in = (const float*)d_in[2];
    const float* Wk   = (const float*)d_in[3];
    const float* bk   = (const float*)d_in[4];
    const float* Wv   = (const float*)d_in[5];
    const float* bv   = (const float*)d_in[6];
    const float* Wq   = (const float*)d_in[7];
    const float* bq   = (const float*)d_in[8];
    const float* Wo   = (const float*)d_in[9];
    const float* bo   = (const float*)d_in[10];
    float* out = (float*)d_out;

    char* p = (char*)d_ws;
    const size_t MB = 1024 * 1024;
    u16* WqH = (u16*)(p + 0 * MB);
    u16* WqL = (u16*)(p + 1 * MB);
    u16* WkH = (u16*)(p + 2 * MB);
    u16* WkL = (u16*)(p + 3 * MB);
    u16* WvH = (u16*)(p + 4 * MB);
    u16* WvL = (u16*)(p + 5 * MB);
    u16* WoH = (u16*)(p + 6 * MB);
    u16* WoL = (u16*)(p + 7 * MB);
    const size_t PB = 32 * MB;
    u16* QH  = (u16*)(p + 8 * MB);
    u16* KH  = (u16*)(p + 8 * MB + 1 * PB);
    u16* VTH = (u16*)(p + 8 * MB + 2 * PB);
    u16* RH  = (u16*)(p + 8 * MB + 3 * PB);
    u16* RL  = (u16*)(p + 8 * MB + 4 * PB);

    prep_w<<<dim3(2048), dim3(256), 0, stream>>>(Wq, WqH, WqL);
    prep_w<<<dim3(2048), dim3(256), 0, stream>>>(Wk, WkH, WkL);
    prep_w<<<dim3(2048), dim3(256), 0, stream>>>(Wv, WvH, WvL);
    prep_wo<<<dim3(256), dim3(256), 0, stream>>>(Wo, WoH, WoL);

    // projections: M=8192, N=2048, K=256.
    // Q scaled by log2(e)/sqrt(D) -> logits directly in log2 domain.
    const float qscale = 1.4426950408889634f / 16.0f;
    gemm_split<0, 0, 1, 128><<<dim3(16, 64), dim3(512), 0, stream>>>(
        q_in, nullptr, nullptr, WqH, WqL, bq, QH, nullptr, 8192, 2048, 256, qscale);
    gemm_split<0, 0, 1, 128><<<dim3(16, 64), dim3(512), 0, stream>>>(
        k_in, nullptr, nullptr, WkH, WkL, bk, KH, nullptr, 8192, 2048, 256, 1.0f);
    gemm_split<1, 0, 2, 128><<<dim3(16, 64), dim3(512), 0, stream>>>(
        v_in, nullptr, nullptr, WvH, WvL, bv, VTH, nullptr, 8192, 2048, 256, 1.0f);

    // flash attention: 16 q-tiles (128 q) x 32 bh = 512 blocks of 256 threads
    attn_kernel<<<dim3(16, 32), dim3(256), 0, stream>>>(
        QH, KH, VTH, RH, RL);

    // output projection: M=8192, N=256, K=2048; A = R [b][h][s][d], k = h*256+d
    gemm_split<2, 2, 3, 64><<<dim3(4, 64), dim3(512), 0, stream>>>(
        nullptr, RH, RL, WoH, WoL, bo, nullptr, out, 8192, 256, 2048, 1.0f);
}

// Round 9
// 356.692 us; speedup vs baseline: 1.6799x; 1.0616x over previous
//
#include <hip/hip_runtime.h>

#define BB 4
#define SS 2048
#define DD 256
#define HH 8

typedef unsigned short u16;
typedef __attribute__((ext_vector_type(8))) short bf16x8;
typedef __attribute__((ext_vector_type(4))) float f32x4;
typedef __attribute__((ext_vector_type(16))) float f32x16;
typedef __attribute__((ext_vector_type(4))) short s16x4;

__device__ __forceinline__ f32x4 MFMA(bf16x8 a, bf16x8 b, f32x4 c) {
    return __builtin_amdgcn_mfma_f32_16x16x32_bf16(a, b, c, 0, 0, 0);
}
__device__ __forceinline__ f32x16 MFMA32(bf16x8 a, bf16x8 b, f32x16 c) {
    return __builtin_amdgcn_mfma_f32_32x32x16_bf16(a, b, c, 0, 0, 0);
}

__device__ __forceinline__ u16 f2bf_rtn(float x) {
    unsigned u = __float_as_uint(x);
    u += 0x7FFFu + ((u >> 16) & 1u);
    return (u16)(u >> 16);
}
__device__ __forceinline__ float bf2f(u16 h) {
    return __uint_as_float(((unsigned)h) << 16);
}
__device__ __forceinline__ void split2(float x, u16 &hi, u16 &lo) {
    hi = f2bf_rtn(x);
    lo = f2bf_rtn(x - bf2f(hi));
}

// async global->LDS, 16B per lane; LDS dest = wave-uniform base + lane*16
__device__ __forceinline__ void gl_lds16(const u16* g, u16* l) {
    __builtin_amdgcn_global_load_lds(
        (const __attribute__((address_space(1))) unsigned int*)(g),
        (__attribute__((address_space(3))) unsigned int*)(l), 16, 0, 0);
}

// ---------------- weight prep ----------------
__global__ void prep_w(const float* __restrict__ W, u16* __restrict__ Whi,
                       u16* __restrict__ Wlo) {
    int n = blockIdx.x;            // 0..2047
    int h = n >> 8, e = n & 255;
    int d = threadIdx.x;           // 0..255
    float x = W[((size_t)h * 256 + d) * 256 + e];
    u16 hi, lo; split2(x, hi, lo);
    Whi[(size_t)n * 256 + d] = hi;
    Wlo[(size_t)n * 256 + d] = lo;
}

// Wo [2048][256] (row = d*8+h) -> Wot[e][h*256+d]
__global__ void prep_wo(const float* __restrict__ W, u16* __restrict__ Whi,
                        u16* __restrict__ Wlo) {
    int n = blockIdx.x;            // e: 0..255
    for (int k = threadIdx.x; k < 2048; k += 256) {
        int d = k & 255, h = k >> 8;
        float x = W[((size_t)(d * 8 + h)) * 256 + n];
        u16 hi, lo; split2(x, hi, lo);
        Whi[(size_t)n * 2048 + k] = hi;
        Wlo[(size_t)n * 2048 + k] = lo;
    }
}

// ---------------- split-bf16 GEMM: C = A * B^T(stored [N][K]) + bias ----------------
// MODE 0: bf16-hi out -> [b][h][s][d]; MODE 1: -> V^T [b][h][d][s]; MODE 2: fp32 out
// AMODE 0: A fp32 [row][k]; AMODE 2: A = R planes [b][h][s][d], k = h*256+d
template<int MODE, int AMODE, int TERMS, int BN>
__global__ __launch_bounds__(512, 2) void gemm_split(
    const float* __restrict__ Af,
    const u16* __restrict__ Ahi, const u16* __restrict__ Alo,
    const u16* __restrict__ Bhi, const u16* __restrict__ Blo,
    const float* __restrict__ bias,
    u16* __restrict__ Ohi,
    float* __restrict__ Of,
    int M, int N, int K, float scale)
{
    constexpr int WN = (BN == 128) ? 4 : 2;
    constexpr int WM = 8 / WN;
    constexpr int MSUB = (128 / WM) / 16;
    constexpr int NSUB = (BN / WN) / 16;

    __shared__ u16 lA_hi[128][40], lA_lo[128][40];
    __shared__ u16 lB_hi[128][40], lB_lo[128][40];

    const int tid = threadIdx.x;
    const int lane = tid & 63, wave = tid >> 6;
    const int wm = wave / WN, wn = wave % WN;
    const int m0 = blockIdx.y * 128, n0 = blockIdx.x * BN;

    f32x4 acc[MSUB][NSUB];
#pragma unroll
    for (int i = 0; i < MSUB; ++i)
#pragma unroll
        for (int j = 0; j < NSUB; ++j) acc[i][j] = {0.f, 0.f, 0.f, 0.f};

    const int srow = tid >> 2;
    const int schunk = (tid & 3) * 8;

    for (int k0 = 0; k0 < K; k0 += 32) {
        __syncthreads();
        if (AMODE == 0) {
            const float* g = Af + (size_t)(m0 + srow) * K + k0 + schunk;
            f32x4 a0 = *(const f32x4*)g;
            f32x4 a1 = *(const f32x4*)(g + 4);
            bf16x8 hv;
#pragma unroll
            for (int j = 0; j < 4; ++j) hv[j] = (short)f2bf_rtn(a0[j]);
#pragma unroll
            for (int j = 0; j < 4; ++j) hv[4 + j] = (short)f2bf_rtn(a1[j]);
            *(bf16x8*)&lA_hi[srow][schunk] = hv;
        } else {
            size_t ga;
            if (AMODE == 2)
                ga = ((size_t)((m0 >> 11) * 8 + (k0 >> 8)) * SS + (m0 & 2047) + srow) * DD
                     + (k0 & 255) + schunk;
            else
                ga = (size_t)(m0 + srow) * K + k0 + schunk;
            *(bf16x8*)&lA_hi[srow][schunk] = *(const bf16x8*)(Ahi + ga);
            if (TERMS == 3)
                *(bf16x8*)&lA_lo[srow][schunk] = *(const bf16x8*)(Alo + ga);
        }
        if (BN == 128 || tid < BN * 4) {
            size_t gb = (size_t)(n0 + srow) * K + k0 + schunk;
            *(bf16x8*)&lB_hi[srow][schunk] = *(const bf16x8*)(Bhi + gb);
            if (TERMS >= 2)
                *(bf16x8*)&lB_lo[srow][schunk] = *(const bf16x8*)(Blo + gb);
        }
        __syncthreads();

        const int kf = (lane >> 4) * 8;
        const int rA = wm * (128 / WM), rB = wn * (BN / WN);
        bf16x8 bh[NSUB], bl[NSUB];
#pragma unroll
        for (int ns = 0; ns < NSUB; ++ns) {
            bh[ns] = *(bf16x8*)&lB_hi[rB + ns * 16 + (lane & 15)][kf];
            if (TERMS >= 2)
                bl[ns] = *(bf16x8*)&lB_lo[rB + ns * 16 + (lane & 15)][kf];
        }
#pragma unroll
        for (int ms = 0; ms < MSUB; ++ms) {
            bf16x8 ah = *(bf16x8*)&lA_hi[rA + ms * 16 + (lane & 15)][kf];
            bf16x8 al;
            if (TERMS == 3) al = *(bf16x8*)&lA_lo[rA + ms * 16 + (lane & 15)][kf];
#pragma unroll
            for (int ns = 0; ns < NSUB; ++ns) {
                acc[ms][ns] = MFMA(ah, bh[ns], acc[ms][ns]);
                if (TERMS == 3) acc[ms][ns] = MFMA(al, bh[ns], acc[ms][ns]);
                if (TERMS >= 2) acc[ms][ns] = MFMA(ah, bl[ns], acc[ms][ns]);
            }
        }
    }

#pragma unroll
    for (int ms = 0; ms < MSUB; ++ms)
#pragma unroll
        for (int ns = 0; ns < NSUB; ++ns)
#pragma unroll
            for (int r = 0; r < 4; ++r) {
                int row = m0 + wm * (128 / WM) + ms * 16 + (lane >> 4) * 4 + r;
                int col = n0 + wn * (BN / WN) + ns * 16 + (lane & 15);
                float v = (acc[ms][ns][r] + bias[col]) * scale;
                if (MODE == 2) {
                    Of[(size_t)row * N + col] = v;
                } else {
                    int b = row >> 11, s = row & 2047, hh = col >> 8, e = col & 255;
                    size_t idx;
                    if (MODE == 0)
                        idx = ((size_t)(b * HH + hh) * SS + s) * DD + e;
                    else
                        idx = ((size_t)(b * HH + hh) * DD + e) * SS + s;
                    Ohi[idx] = f2bf_rtn(v);
                }
            }
}

// ---------------- flash attention: 32x32x16 MFMA, global_load_lds, fixed-m softmax ----
// 4 waves x 32 q = 128 q/block; KVBLK=32; 2 blocks/CU (64 KB LDS each).
// 1-D grid with bijective XCD swizzle: 64 consecutive wgs per XCD = 4 bh x 16 q-tiles,
// so each XCD fetches its K/V once (L2-resident ~128 KB/tile working set) and the two
// co-resident blocks on a CU read the SAME tile (L1/L2 hits -> fast drain).
// Swapped QK^T with key permutation kappa = swap bits 2<->3 (involution), which makes
// the exp'd S^T registers sequential PV B-fragments: pb_kc[j] = s[8*kc + j].
// K LDS [32][256]: row r holds key kappa(r), 16B-slot X stores d-slot X^r.
// V LDS [256][32]: row e, slot Xs stores k-slot Xs^((e>>3)&3). Both: reads and the
// lane-linear global_load_lds writes hit exactly 2 lanes per 16B slot (conflict-free).
// Fixed softmax ref m=8 (log2-domain logits, |s|<<8): no max, no rescale; l deferred.
__global__ __launch_bounds__(256, 2) void attn_kernel(
    const u16* __restrict__ Qhi,
    const u16* __restrict__ Khi,
    const u16* __restrict__ Vhi,
    u16* __restrict__ Rhi, u16* __restrict__ Rlo)
{
    __shared__ u16 lK[2][32][256];
    __shared__ u16 lV[2][256][32];

    const int tid = threadIdx.x, lane = tid & 63, wave = tid >> 6;
    const int qc = lane & 31, g2 = lane >> 5;
    // XCD swizzle: 512 blocks; wg = (bid%8)*64 + bid/8 (bijective, 512 = 8*64)
    const int wg = ((blockIdx.x & 7) << 6) + (blockIdx.x >> 3);
    const int bh = wg >> 4;                        // 0..31
    const int qt = wg & 15;                        // 0..15
    const size_t base = (size_t)bh * SS * DD;
    const int q0w = qt * 128 + wave * 32;

    // Q as B-operand: lane holds Q[d = ks*16 + g2*8 + j][q = qc]
    bf16x8 qB[16];
#pragma unroll
    for (int ks = 0; ks < 16; ++ks)
        qB[ks] = *(const bf16x8*)(Qhi + base + (size_t)(q0w + qc) * DD + ks * 16 + g2 * 8);

    // per-lane global source offsets for the 8 gl_lds16 issues (K:4, V:4)
    int koff[4], voff[4];
#pragma unroll
    for (int q = 0; q < 4; ++q) {
        const int s = wave * 256 + q * 64 + lane;  // linear 16B-slot in 16KB image
        const int kr = s >> 5, kX = s & 31;
        const int kap = (kr & 0x13) | ((kr & 4) << 1) | ((kr & 8) >> 1);
        koff[q] = kap * DD + ((kX ^ kr) << 3);
        const int ve = s >> 2, vXs = s & 3;
        voff[q] = ve * SS + (((vXs ^ ((ve >> 3) & 3))) << 3);
    }

    float l_part = 0.f;
    f32x16 acc[8];
#pragma unroll
    for (int ec = 0; ec < 8; ++ec) acc[ec] = {};

#define ISSUE(tt, p)                                                            \
    {   const u16* Kg = Khi + base + (size_t)(tt) * 32 * DD;                    \
        const u16* Vg = Vhi + base + (size_t)(tt) * 32;                         \
        u16* Kb = &lK[p][0][0]; u16* Vb = &lV[p][0][0];                         \
        _Pragma("unroll")                                                       \
        for (int q = 0; q < 4; ++q) {                                           \
            gl_lds16(Kg + koff[q], Kb + (wave * 4 + q) * 512);                  \
            gl_lds16(Vg + voff[q], Vb + (wave * 4 + q) * 512);                  \
        }                                                                       \
    }

    ISSUE(0, 0);
    __syncthreads();

    for (int t = 0; t < 64; ++t) {
        if (t < 63) ISSUE(t + 1, (t + 1) & 1);

        const u16* Kb = &lK[t & 1][0][0];
        const u16* Vb = &lV[t & 1][0][0];

        // QK^T: two independent 8-chains over d (d-split), merged after
        f32x16 sa = {}, sb = {};
        __builtin_amdgcn_s_setprio(1);
#pragma unroll
        for (int ks = 0; ks < 8; ++ks) {
            bf16x8 ka = *(const bf16x8*)(Kb + qc * DD + (((2 * ks + g2) ^ qc) << 3));
            bf16x8 kb2 = *(const bf16x8*)(Kb + qc * DD + (((2 * (ks + 8) + g2) ^ qc) << 3));
            sa = MFMA32(ka, qB[ks], sa);
            sb = MFMA32(kb2, qB[ks + 8], sb);
        }
        __builtin_amdgcn_s_setprio(0);

        // fixed-m softmax in log2 domain; l deferred (lane-local scalar)
        f32x16 s = sa + sb;
#pragma unroll
        for (int n = 0; n < 16; ++n) s[n] = __builtin_amdgcn_exp2f(s[n] - 8.0f);
        float tl = 0.f;
#pragma unroll
        for (int n = 0; n < 16; ++n) tl += s[n];
        l_part += tl;

        bf16x8 p0, p1;
#pragma unroll
        for (int j = 0; j < 8; ++j) p0[j] = (short)f2bf_rtn(s[j]);
#pragma unroll
        for (int j = 0; j < 8; ++j) p1[j] = (short)f2bf_rtn(s[8 + j]);

        // PV: acc[ec] over e = ec*32 + row
        __builtin_amdgcn_s_setprio(1);
#pragma unroll
        for (int ec = 0; ec < 8; ++ec) {
            const int e = ec * 32 + qc;
            bf16x8 v0 = *(const bf16x8*)(Vb + e * 32 + (((g2 ^ ((e >> 3) & 3))) << 3));
            bf16x8 v1 = *(const bf16x8*)(Vb + e * 32 + ((((2 + g2) ^ ((e >> 3) & 3))) << 3));
            acc[ec] = MFMA32(v0, p0, acc[ec]);
            acc[ec] = MFMA32(v1, p1, acc[ec]);
        }
        __builtin_amdgcn_s_setprio(0);

        __syncthreads();
    }
#undef ISSUE

    // epilogue: l = own half + partner half (lane^32 shares qc); store R [bh][s][d]
    float l = l_part + __shfl_xor(l_part, 32);
    float inv = 1.0f / l;
    const size_t rowbase = ((size_t)bh * SS + q0w + qc) * DD;
#pragma unroll
    for (int ec = 0; ec < 8; ++ec)
#pragma unroll
        for (int rr = 0; rr < 4; ++rr) {
            const int e0 = ec * 32 + 8 * rr + 4 * g2;
            s16x4 hv, lv;
#pragma unroll
            for (int j = 0; j < 4; ++j) {
                u16 h2, l2; split2(acc[ec][4 * rr + j] * inv, h2, l2);
                hv[j] = (short)h2; lv[j] = (short)l2;
            }
            *(s16x4*)(Rhi + rowbase + e0) = hv;
            *(s16x4*)(Rlo + rowbase + e0) = lv;
        }
}

// ---------------- launcher ----------------
extern "C" void kernel_launch(void* const* d_in, const int* in_sizes, int n_in,
                              void* d_out, int out_size, void* d_ws, size_t ws_size,
                              hipStream_t stream)
{
    (void)in_sizes; (void)n_in; (void)out_size; (void)ws_size;
    const float* k_in = (const float*)d_in[0];
    const float* v_in = (const float*)d_in[1];
    const float* q_in = (const float*)d_in[2];
    const float* Wk   = (const float*)d_in[3];
    const float* bk   = (const float*)d_in[4];
    const float* Wv   = (const float*)d_in[5];
    const float* bv   = (const float*)d_in[6];
    const float* Wq   = (const float*)d_in[7];
    const float* bq   = (const float*)d_in[8];
    const float* Wo   = (const float*)d_in[9];
    const float* bo   = (const float*)d_in[10];
    float* out = (float*)d_out;

    char* p = (char*)d_ws;
    const size_t MB = 1024 * 1024;
    u16* WqH = (u16*)(p + 0 * MB);
    u16* WqL = (u16*)(p + 1 * MB);
    u16* WkH = (u16*)(p + 2 * MB);
    u16* WkL = (u16*)(p + 3 * MB);
    u16* WvH = (u16*)(p + 4 * MB);
    u16* WvL = (u16*)(p + 5 * MB);
    u16* WoH = (u16*)(p + 6 * MB);
    u16* WoL = (u16*)(p + 7 * MB);
    const size_t PB = 32 * MB;
    u16* QH  = (u16*)(p + 8 * MB);
    u16* KH  = (u16*)(p + 8 * MB + 1 * PB);
    u16* VTH = (u16*)(p + 8 * MB + 2 * PB);
    u16* RH  = (u16*)(p + 8 * MB + 3 * PB);
    u16* RL  = (u16*)(p + 8 * MB + 4 * PB);

    prep_w<<<dim3(2048), dim3(256), 0, stream>>>(Wq, WqH, WqL);
    prep_w<<<dim3(2048), dim3(256), 0, stream>>>(Wk, WkH, WkL);
    prep_w<<<dim3(2048), dim3(256), 0, stream>>>(Wv, WvH, WvL);
    prep_wo<<<dim3(256), dim3(256), 0, stream>>>(Wo, WoH, WoL);

    // projections: M=8192, N=2048, K=256.
    // Q scaled by log2(e)/sqrt(D) -> logits directly in log2 domain.
    const float qscale = 1.4426950408889634f / 16.0f;
    gemm_split<0, 0, 1, 128><<<dim3(16, 64), dim3(512), 0, stream>>>(
        q_in, nullptr, nullptr, WqH, WqL, bq, QH, nullptr, 8192, 2048, 256, qscale);
    gemm_split<0, 0, 1, 128><<<dim3(16, 64), dim3(512), 0, stream>>>(
        k_in, nullptr, nullptr, WkH, WkL, bk, KH, nullptr, 8192, 2048, 256, 1.0f);
    gemm_split<1, 0, 2, 128><<<dim3(16, 64), dim3(512), 0, stream>>>(
        v_in, nullptr, nullptr, WvH, WvL, bv, VTH, nullptr, 8192, 2048, 256, 1.0f);

    // flash attention: 512 blocks (16 q-tiles x 32 bh), XCD-swizzled 1-D grid
    attn_kernel<<<dim3(512), dim3(256), 0, stream>>>(
        QH, KH, VTH, RH, RL);

    // output projection: M=8192, N=256, K=2048; A = R [b][h][s][d], k = h*256+d
    gemm_split<2, 2, 3, 64><<<dim3(4, 64), dim3(512), 0, stream>>>(
        nullptr, RH, RL, WoH, WoL, bo, nullptr, out, 8192, 256, 2048, 1.0f);
}